// Round 7
// baseline (323.481 us; speedup 1.0000x reference)
//
#include <hip/hip_runtime.h>

typedef unsigned int uint;
#define LOG2E 1.4426950408889634f

__device__ __forceinline__ float bf16_lo(uint v) { return __uint_as_float(v << 16); }
__device__ __forceinline__ float bf16_hi(uint v) { return __uint_as_float(v & 0xffff0000u); }
__device__ __forceinline__ unsigned short f2bf(float f) {
    uint u = __float_as_uint(f);
    return (unsigned short)((u + 0x7fffu + ((u >> 16) & 1u)) >> 16);  // RNE
}
__device__ __forceinline__ float bf16u(uint s) {
    return __uint_as_float(s << 16);
}

// ---------------------------------------------------------------------------
// Projection body: out[row][c] = X[row,:K] @ W[:K,c] + b[c]  (64 rows/block)
// thread t: row-quad rquad=t>>4, col-quad cq=t&15.
// X staged in LDS (17.4KB); W read from global (16KB, L1-resident across all
// blocks on the CU -> frees LDS so 8 blocks/CU fit; occupancy was the limit).
// Attention sums pre-scaled by LOG2E (downstream logits in log2 domain).
// ---------------------------------------------------------------------------
template<int K>
__device__ __forceinline__ void proj_body(
    int blk, const float* __restrict__ X, const float* __restrict__ W,
    const float* __restrict__ bias, const float* __restrict__ avec0,
    const float* __restrict__ avec1, int mode, int nrows,
    float* __restrict__ outF32, unsigned short* __restrict__ outF16,
    float2* __restrict__ outA0, float2* __restrict__ outA1,
    float* Xsh, float* av0sh, float* av1sh, float* bsh)
{
    constexpr int XP = 68;
    int t = threadIdx.x;

    if (t < 64) {
        int head = t >> 5, d = t & 31;
        int aidx = (mode == 0) ? t : (mode == 1 ? head * 64 + d : head * 64 + 32 + d);
        av0sh[t] = avec0 ? avec0[aidx] : 0.f;
        av1sh[t] = avec1 ? avec1[aidx] : 0.f;
        bsh[t] = bias[t];
    }

    int base = blk * 64;
    const float4* X4 = (const float4*)X;
    for (int i = t; i < 64 * (K / 4); i += 256) {
        int row = i / (K / 4), c4 = i % (K / 4);
        int gr = base + row; if (gr >= nrows) gr = nrows - 1;
        *(float4*)&Xsh[row * XP + c4 * 4] = X4[(size_t)gr * (K / 4) + c4];
    }
    __syncthreads();

    const float4* __restrict__ W4 = (const float4*)W;
    int rquad = t >> 4, cq = t & 15;
    float acc[4][4];
#pragma unroll
    for (int ri = 0; ri < 4; ++ri)
#pragma unroll
        for (int ci = 0; ci < 4; ++ci) acc[ri][ci] = 0.f;

#pragma unroll 4
    for (int kq = 0; kq < K / 4; ++kq) {
        float4 wq0 = W4[(4 * kq + 0) * 16 + cq];
        float4 wq1 = W4[(4 * kq + 1) * 16 + cq];
        float4 wq2 = W4[(4 * kq + 2) * 16 + cq];
        float4 wq3 = W4[(4 * kq + 3) * 16 + cq];
#pragma unroll
        for (int ri = 0; ri < 4; ++ri) {
            float4 xq = *(const float4*)&Xsh[(4 * rquad + ri) * XP + 4 * kq];
            acc[ri][0] += xq.x * wq0.x + xq.y * wq1.x + xq.z * wq2.x + xq.w * wq3.x;
            acc[ri][1] += xq.x * wq0.y + xq.y * wq1.y + xq.z * wq2.y + xq.w * wq3.y;
            acc[ri][2] += xq.x * wq0.z + xq.y * wq1.z + xq.z * wq2.z + xq.w * wq3.z;
            acc[ri][3] += xq.x * wq0.w + xq.y * wq1.w + xq.z * wq2.w + xq.w * wq3.w;
        }
    }

    int c0 = cq * 4;
    float4 bv  = *(float4*)&bsh[c0];
    float4 a0v = *(float4*)&av0sh[c0];
    float4 a1v = *(float4*)&av1sh[c0];
    float4 vv[4];
    float s0[4], s1[4];
#pragma unroll
    for (int ri = 0; ri < 4; ++ri) {
        float4 val;
        val.x = acc[ri][0] + bv.x;
        val.y = acc[ri][1] + bv.y;
        val.z = acc[ri][2] + bv.z;
        val.w = acc[ri][3] + bv.w;
        vv[ri] = val;
        float r0 = fmaxf(val.x, 0.f), r1 = fmaxf(val.y, 0.f);
        float r2 = fmaxf(val.z, 0.f), r3 = fmaxf(val.w, 0.f);
        s0[ri] = r0 * a0v.x + r1 * a0v.y + r2 * a0v.z + r3 * a0v.w;
        s1[ri] = r0 * a1v.x + r1 * a1v.y + r2 * a1v.z + r3 * a1v.w;
    }
#pragma unroll
    for (int ri = 0; ri < 4; ++ri) {
        s0[ri] += __shfl_xor(s0[ri], 1, 64);
        s0[ri] += __shfl_xor(s0[ri], 2, 64);
        s0[ri] += __shfl_xor(s0[ri], 4, 64);
        s1[ri] += __shfl_xor(s1[ri], 1, 64);
        s1[ri] += __shfl_xor(s1[ri], 2, 64);
        s1[ri] += __shfl_xor(s1[ri], 4, 64);
    }
    float s0x[4], s1x[4];
#pragma unroll
    for (int ri = 0; ri < 4; ++ri) {
        s0x[ri] = __shfl_xor(s0[ri], 8, 64);
        s1x[ri] = __shfl_xor(s1[ri], 8, 64);
    }

    int rbase = base + rquad * 4;
#pragma unroll
    for (int ri = 0; ri < 4; ++ri) {
        int row = rbase + ri;
        if (row >= nrows) continue;
        if (outF32)
            *(float4*)&outF32[(size_t)row * 64 + c0] = vv[ri];
        uint u0 = (uint)f2bf(vv[ri].x) | ((uint)f2bf(vv[ri].y) << 16);
        uint u1 = (uint)f2bf(vv[ri].z) | ((uint)f2bf(vv[ri].w) << 16);
        *(uint2*)&outF16[(size_t)row * 64 + c0] = make_uint2(u0, u1);
        if (cq == 0 && outA0)
            outA0[row] = make_float2(s0[ri] * LOG2E, s0x[ri] * LOG2E);
        if (cq == 1 && outA1)
            outA1[row] = make_float2(s1[ri] * LOG2E, s1x[ri] * LOG2E);
    }
}

// ---------------------------------------------------------------------------
// Mega kernel: segments [C: rel proj | A: target proj | B: mid proj | D: deg]
// ---------------------------------------------------------------------------
__global__ __launch_bounds__(256) void mega_kernel(
    const float* __restrict__ h, const float* __restrict__ W_t, const float* __restrict__ b_t,
    const float* __restrict__ nfeat_mid, const float* __restrict__ W_mid, const float* __restrict__ b_mid,
    const float* __restrict__ efeat_rel, const float* __restrict__ W_rel, const float* __restrict__ b_rel,
    const float* __restrict__ attn_src, const float* __restrict__ attn_dst, const float* __restrict__ attn_edge,
    const int* __restrict__ dst_idx, int* __restrict__ deg,
    float* __restrict__ hp32, unsigned short* __restrict__ hp16,
    unsigned short* __restrict__ mid16, unsigned short* __restrict__ rel16,
    float2* __restrict__ e_src, float2* __restrict__ e_dst,
    float2* __restrict__ em, float2* __restrict__ er,
    int N, int EREL, int E, int nC, int nA, int nB)
{
    __shared__ float Xsh[64 * 68];
    __shared__ float av0sh[64], av1sh[64], bsh[64];
    int b = blockIdx.x;
    if (b < nC) {
        proj_body<32>(b, efeat_rel, W_rel, b_rel, attn_edge, nullptr, 2, EREL,
                      nullptr, rel16, er, nullptr, Xsh, av0sh, av1sh, bsh);
    } else if (b < nC + nA) {
        proj_body<64>(b - nC, h, W_t, b_t, attn_src, attn_dst, 0, N,
                      hp32, hp16, e_src, e_dst, Xsh, av0sh, av1sh, bsh);
    } else if (b < nC + nA + nB) {
        proj_body<64>(b - nC - nA, nfeat_mid, W_mid, b_mid, attn_edge, nullptr, 1, N,
                      nullptr, mid16, em, nullptr, Xsh, av0sh, av1sh, bsh);
    } else {
        int i = (b - nC - nA - nB) * 256 + threadIdx.x;
        if (i < E) atomicAdd(&deg[dst_idx[i]], 1);
    }
}

// ---------------------------------------------------------------------------
__global__ __launch_bounds__(256) void scanA_kernel(
    const int* __restrict__ deg, int* __restrict__ blkSums, int N)
{
    __shared__ int red[256];
    int t = threadIdx.x;
    int base = blockIdx.x * 1024 + t * 4;
    int s = 0;
    if (base + 3 < N) {
        int4 v = *(const int4*)&deg[base];
        s = v.x + v.y + v.z + v.w;
    } else {
        for (int i = 0; i < 4; ++i) if (base + i < N) s += deg[base + i];
    }
    red[t] = s;
    __syncthreads();
    for (int off = 128; off >= 1; off >>= 1) {
        if (t < off) red[t] += red[t + off];
        __syncthreads();
    }
    if (t == 0) blkSums[blockIdx.x] = red[0];
}

// ---------------------------------------------------------------------------
__global__ __launch_bounds__(256) void scanC_kernel(
    const int* __restrict__ deg, const int* __restrict__ blkSums,
    int* __restrict__ row_ptr, int* __restrict__ cursor, int N, int nblk)
{
    __shared__ int sh[256];
    __shared__ int blkOffSh;
    int t = threadIdx.x;
    int blk = blockIdx.x;
    int base = blk * 1024 + t * 4;

    if (t < 64) {
        int s = 0;
        for (int j = t; j < blk; j += 64) s += blkSums[j];
        for (int m = 32; m >= 1; m >>= 1) s += __shfl_xor(s, m, 64);
        if (t == 0) blkOffSh = s;
    }

    int4 v = make_int4(0, 0, 0, 0);
    if (base + 3 < N) v = *(const int4*)&deg[base];
    else {
        if (base < N)     v.x = deg[base];
        if (base + 1 < N) v.y = deg[base + 1];
        if (base + 2 < N) v.z = deg[base + 2];
    }
    int ts = v.x + v.y + v.z + v.w;
    sh[t] = ts;
    __syncthreads();
    for (int off = 1; off < 256; off <<= 1) {
        int val = (t >= off) ? sh[t - off] : 0;
        __syncthreads();
        sh[t] += val;
        __syncthreads();
    }
    int blkOff = blkOffSh;
    int ex = blkOff + ((t == 0) ? 0 : sh[t - 1]);
    int p0 = ex, p1 = ex + v.x, p2 = p1 + v.y, p3 = p2 + v.z;
    if (base < N)     { row_ptr[base]     = p0; cursor[base]     = p0; }
    if (base + 1 < N) { row_ptr[base + 1] = p1; cursor[base + 1] = p1; }
    if (base + 2 < N) { row_ptr[base + 2] = p2; cursor[base + 2] = p2; }
    if (base + 3 < N) { row_ptr[base + 3] = p3; cursor[base + 3] = p3; }
    if (blk == nblk - 1 && t == 255) row_ptr[N] = blkOff + sh[255];
}

// ---------------------------------------------------------------------------
// Fused edge-logit + CSR scatter. One packed 16B record per edge:
//   { src | (hn<<16), he, e_head0_bits, e_head1_bits }  (log2 domain, ±60 clamp)
// ---------------------------------------------------------------------------
__global__ __launch_bounds__(256) void scatter_kernel(
    const int* __restrict__ src, const int* __restrict__ dst,
    const int* __restrict__ hn, const int* __restrict__ he,
    const float2* __restrict__ es, const float2* __restrict__ ed,
    const float2* __restrict__ em, const float2* __restrict__ er,
    int* __restrict__ cursor, uint4* __restrict__ erec, int E)
{
    int i = blockIdx.x * blockDim.x + threadIdx.x;
    if (i >= E) return;
    int s = src[i], d = dst[i], a = hn[i], b = he[i];
    float2 v1 = es[s], v2 = ed[d], v3 = em[a], v4 = er[b];
    float e0 = fminf(fmaxf(v1.x + v2.x + v3.x + v4.x, -60.f), 60.f);
    float e1 = fminf(fmaxf(v1.y + v2.y + v3.y + v4.y, -60.f), 60.f);
    int pos = atomicAdd(&cursor[d], 1);
    erec[pos] = make_uint4((uint)s | ((uint)a << 16), (uint)b,
                           __float_as_uint(e0), __float_as_uint(e1));
}

// ---------------------------------------------------------------------------
// Per-node aggregation, single pass, 1-deep software pipeline: prefetch the
// next edge record + its gathers into named registers while computing the
// current one (compiler alone allocated ~20 VGPRs and serialized the chain;
// R5 showed VALUBusy 46% = latency-bound at exactly the predicted ratio).
// ---------------------------------------------------------------------------
__global__ __launch_bounds__(256) void aggregate_kernel(
    const int* __restrict__ row_ptr, const uint4* __restrict__ erec,
    const float* __restrict__ hp32,
    const unsigned short* __restrict__ hp16,
    const unsigned short* __restrict__ mid16,
    const unsigned short* __restrict__ rel16,
    const float* __restrict__ We, const float* __restrict__ be,
    float* __restrict__ out, int N)
{
    __shared__ float WeSh[64 * 32];
    __shared__ float ft2sh[4][128];
    int t = threadIdx.x;
    for (int i = t; i < 64 * 32; i += 256) WeSh[i] = We[i];
    __syncthreads();

    int wave = t >> 6, lane = t & 63;
    int head = lane >> 5, dj = lane & 31;
    int n = blockIdx.x * 4 + wave;
    bool valid = n < N;
    int nn = valid ? n : 0;

    int start = row_ptr[nn], end = row_ptr[nn + 1];
    int cnt = end - start;

    bool isrel = lane >= 32;
    int l31 = lane & 31;
    bool h1w = ((lane >> 4) & 1) != 0;
    const uint* tab32 = (const uint*)(isrel ? rel16 : mid16);
    float rstc = 0.f, fx = 0.f, fy = 0.f, den0 = 0.f, den1 = 0.f;

    uint4 rec0 = make_uint4(0, 0, 0, 0);
    uint hu0 = 0, pv0 = 0;
    if (cnt > 0) {
        rec0 = erec[start];
        hu0 = (uint)hp16[((rec0.x & 0xffffu) << 6) | (uint)lane];
        pv0 = tab32[((isrel ? rec0.y : (rec0.x >> 16)) << 5) | (uint)l31];
    }
    for (int i = 0; i < cnt; ++i) {
        int j = start + i + 1;
        int jj = (j < end) ? j : start;          // dummy (re)load, values unused
        uint4 recN = erec[jj];
        uint huN = (uint)hp16[((recN.x & 0xffffu) << 6) | (uint)lane];
        uint pvN = tab32[((isrel ? recN.y : (recN.x >> 16)) << 5) | (uint)l31];

        float a0 = __builtin_amdgcn_exp2f(__uint_as_float(rec0.z));
        float a1 = __builtin_amdgcn_exp2f(__uint_as_float(rec0.w));
        den0 += a0; den1 += a1;
        rstc += bf16u(hu0) * (head ? a1 : a0);
        float w = h1w ? a1 : a0;
        fx += bf16_lo(pv0) * w;
        fy += bf16_hi(pv0) * w;

        rec0 = recN; hu0 = huN; pv0 = pvN;
    }
    float inv0 = den0 > 0.f ? 1.f / den0 : 0.f;
    float inv1 = den1 > 0.f ? 1.f / den1 : 0.f;
    rstc *= head ? inv1 : inv0;
    float invf = h1w ? inv1 : inv0;

    int slotbase;
    if (lane < 16)      slotbase = 2 * lane;
    else if (lane < 32) slotbase = 2 * lane + 32;
    else if (lane < 48) slotbase = 2 * lane - 32;
    else                slotbase = 2 * lane;
    ft2sh[wave][slotbase]     = fx * invf;
    ft2sh[wave][slotbase + 1] = fy * invf;

    // wave-local LDS fence (ft2sh region is per-wave)
    __builtin_amdgcn_sched_barrier(0);
    asm volatile("s_waitcnt lgkmcnt(0)" ::: "memory");
    __builtin_amdgcn_sched_barrier(0);

    float fc = be[dj];
#pragma unroll 8
    for (int dd = 0; dd < 64; ++dd)
        fc += ft2sh[wave][head * 64 + dd] * WeSh[dd * 32 + dj];

    float val = rstc + fc + hp32[(uint)nn * 64 + lane];
    val = fmaxf(val, 0.f);

    float ss = val * val;
    for (int m = 32; m >= 1; m >>= 1) ss += __shfl_xor(ss, m, 64);
    float invn = 1.f / fmaxf(sqrtf(ss), 1e-12f);
    if (valid) out[(uint)nn * 64 + lane] = val * invn;
}

// ---------------------------------------------------------------------------
extern "C" void kernel_launch(void* const* d_in, const int* in_sizes, int n_in,
                              void* d_out, int out_size, void* d_ws, size_t ws_size,
                              hipStream_t stream)
{
    const float* h         = (const float*)d_in[0];
    const float* W_t       = (const float*)d_in[1];
    const float* b_t       = (const float*)d_in[2];
    const float* nfeat_mid = (const float*)d_in[3];
    const float* W_mid     = (const float*)d_in[4];
    const float* b_mid     = (const float*)d_in[5];
    const float* efeat_rel = (const float*)d_in[6];
    const float* W_rel     = (const float*)d_in[7];
    const float* b_rel     = (const float*)d_in[8];
    const float* attn_src  = (const float*)d_in[9];
    const float* attn_dst  = (const float*)d_in[10];
    const float* attn_edge = (const float*)d_in[11];
    const float* W_edge    = (const float*)d_in[12];
    const float* b_edge    = (const float*)d_in[13];
    const int* src_idx     = (const int*)d_in[14];
    const int* dst_idx     = (const int*)d_in[15];
    const int* hn          = (const int*)d_in[16];
    const int* he          = (const int*)d_in[17];
    float* out = (float*)d_out;

    const int N    = in_sizes[0] / 64;
    const int EREL = in_sizes[6] / 32;
    const int E    = in_sizes[14];

    char* ws = (char*)d_ws;
    auto alloc = [&](size_t bytes) {
        void* p = (void*)ws;
        ws += (bytes + 255) & ~(size_t)255;
        return p;
    };
    float* hp32           = (float*)alloc((size_t)N * 64 * 4);
    unsigned short* hp16  = (unsigned short*)alloc((size_t)N * 64 * 2);
    unsigned short* mid16 = (unsigned short*)alloc((size_t)N * 64 * 2);
    unsigned short* rel16 = (unsigned short*)alloc((size_t)EREL * 64 * 2);
    float2* e_src  = (float2*)alloc((size_t)N * 8);
    float2* e_dst  = (float2*)alloc((size_t)N * 8);
    float2* em     = (float2*)alloc((size_t)N * 8);
    float2* er     = (float2*)alloc((size_t)EREL * 8);
    int* deg       = (int*)alloc((size_t)N * 4);
    int* row_ptr   = (int*)alloc((size_t)(N + 1) * 4);
    int* cursor    = (int*)alloc((size_t)N * 4);
    int* blkSums   = (int*)alloc((size_t)64 * 4);
    uint4* erec    = (uint4*)alloc((size_t)E * 16);

    hipMemsetAsync(deg, 0, (size_t)N * 4, stream);

    int nA = (N + 63) / 64;
    int nB = nA;
    int nC = (EREL + 63) / 64;
    int nD = (E + 255) / 256;
    mega_kernel<<<nC + nA + nB + nD, 256, 0, stream>>>(
        h, W_t, b_t, nfeat_mid, W_mid, b_mid, efeat_rel, W_rel, b_rel,
        attn_src, attn_dst, attn_edge, dst_idx, deg,
        hp32, hp16, mid16, rel16, e_src, e_dst, em, er,
        N, EREL, E, nC, nA, nB);

    int nblk = (N + 1023) / 1024;
    scanA_kernel<<<nblk, 256, 0, stream>>>(deg, blkSums, N);
    scanC_kernel<<<nblk, 256, 0, stream>>>(deg, blkSums, row_ptr, cursor, N, nblk);

    scatter_kernel<<<(E + 255) / 256, 256, 0, stream>>>(
        src_idx, dst_idx, hn, he, e_src, e_dst, em, er, cursor, erec, E);

    aggregate_kernel<<<(N + 3) / 4, 256, 0, stream>>>(
        row_ptr, erec, hp32, hp16, mid16, rel16, W_edge, b_edge, out, N);
}

// Round 8
// 301.887 us; speedup vs baseline: 1.0715x; 1.0715x over previous
//
#include <hip/hip_runtime.h>

typedef unsigned int uint;
#define LOG2E 1.4426950408889634f

__device__ __forceinline__ float bf16_lo(uint v) { return __uint_as_float(v << 16); }
__device__ __forceinline__ float bf16_hi(uint v) { return __uint_as_float(v & 0xffff0000u); }
__device__ __forceinline__ unsigned short f2bf(float f) {
    uint u = __float_as_uint(f);
    return (unsigned short)((u + 0x7fffu + ((u >> 16) & 1u)) >> 16);  // RNE
}
__device__ __forceinline__ float bf16u(uint s) {
    return __uint_as_float(s << 16);
}

// ---------------------------------------------------------------------------
// Projection body: out[row][c] = X[row,:K] @ W[:K,c] + b[c]  (64 rows/block)
// X staged in LDS; W streamed from global (L1-resident, shared by all blocks).
// Attention sums pre-scaled by LOG2E (downstream logits in log2 domain).
// ---------------------------------------------------------------------------
template<int K>
__device__ __forceinline__ void proj_body(
    int blk, const float* __restrict__ X, const float* __restrict__ W,
    const float* __restrict__ bias, const float* __restrict__ avec0,
    const float* __restrict__ avec1, int mode, int nrows,
    float* __restrict__ outF32, unsigned short* __restrict__ outF16,
    float2* __restrict__ outA0, float2* __restrict__ outA1,
    float* Xsh, float* av0sh, float* av1sh, float* bsh)
{
    constexpr int XP = 68;
    int t = threadIdx.x;

    if (t < 64) {
        int head = t >> 5, d = t & 31;
        int aidx = (mode == 0) ? t : (mode == 1 ? head * 64 + d : head * 64 + 32 + d);
        av0sh[t] = avec0 ? avec0[aidx] : 0.f;
        av1sh[t] = avec1 ? avec1[aidx] : 0.f;
        bsh[t] = bias[t];
    }

    int base = blk * 64;
    const float4* X4 = (const float4*)X;
    for (int i = t; i < 64 * (K / 4); i += 256) {
        int row = i / (K / 4), c4 = i % (K / 4);
        int gr = base + row; if (gr >= nrows) gr = nrows - 1;
        *(float4*)&Xsh[row * XP + c4 * 4] = X4[(size_t)gr * (K / 4) + c4];
    }
    __syncthreads();

    const float4* __restrict__ W4 = (const float4*)W;
    int rquad = t >> 4, cq = t & 15;
    float acc[4][4];
#pragma unroll
    for (int ri = 0; ri < 4; ++ri)
#pragma unroll
        for (int ci = 0; ci < 4; ++ci) acc[ri][ci] = 0.f;

#pragma unroll 4
    for (int kq = 0; kq < K / 4; ++kq) {
        float4 wq0 = W4[(4 * kq + 0) * 16 + cq];
        float4 wq1 = W4[(4 * kq + 1) * 16 + cq];
        float4 wq2 = W4[(4 * kq + 2) * 16 + cq];
        float4 wq3 = W4[(4 * kq + 3) * 16 + cq];
#pragma unroll
        for (int ri = 0; ri < 4; ++ri) {
            float4 xq = *(const float4*)&Xsh[(4 * rquad + ri) * XP + 4 * kq];
            acc[ri][0] += xq.x * wq0.x + xq.y * wq1.x + xq.z * wq2.x + xq.w * wq3.x;
            acc[ri][1] += xq.x * wq0.y + xq.y * wq1.y + xq.z * wq2.y + xq.w * wq3.y;
            acc[ri][2] += xq.x * wq0.z + xq.y * wq1.z + xq.z * wq2.z + xq.w * wq3.z;
            acc[ri][3] += xq.x * wq0.w + xq.y * wq1.w + xq.z * wq2.w + xq.w * wq3.w;
        }
    }

    int c0 = cq * 4;
    float4 bv  = *(float4*)&bsh[c0];
    float4 a0v = *(float4*)&av0sh[c0];
    float4 a1v = *(float4*)&av1sh[c0];
    float4 vv[4];
    float s0[4], s1[4];
#pragma unroll
    for (int ri = 0; ri < 4; ++ri) {
        float4 val;
        val.x = acc[ri][0] + bv.x;
        val.y = acc[ri][1] + bv.y;
        val.z = acc[ri][2] + bv.z;
        val.w = acc[ri][3] + bv.w;
        vv[ri] = val;
        float r0 = fmaxf(val.x, 0.f), r1 = fmaxf(val.y, 0.f);
        float r2 = fmaxf(val.z, 0.f), r3 = fmaxf(val.w, 0.f);
        s0[ri] = r0 * a0v.x + r1 * a0v.y + r2 * a0v.z + r3 * a0v.w;
        s1[ri] = r0 * a1v.x + r1 * a1v.y + r2 * a1v.z + r3 * a1v.w;
    }
#pragma unroll
    for (int ri = 0; ri < 4; ++ri) {
        s0[ri] += __shfl_xor(s0[ri], 1, 64);
        s0[ri] += __shfl_xor(s0[ri], 2, 64);
        s0[ri] += __shfl_xor(s0[ri], 4, 64);
        s1[ri] += __shfl_xor(s1[ri], 1, 64);
        s1[ri] += __shfl_xor(s1[ri], 2, 64);
        s1[ri] += __shfl_xor(s1[ri], 4, 64);
    }
    float s0x[4], s1x[4];
#pragma unroll
    for (int ri = 0; ri < 4; ++ri) {
        s0x[ri] = __shfl_xor(s0[ri], 8, 64);
        s1x[ri] = __shfl_xor(s1[ri], 8, 64);
    }

    int rbase = base + rquad * 4;
#pragma unroll
    for (int ri = 0; ri < 4; ++ri) {
        int row = rbase + ri;
        if (row >= nrows) continue;
        if (outF32)
            *(float4*)&outF32[(size_t)row * 64 + c0] = vv[ri];
        uint u0 = (uint)f2bf(vv[ri].x) | ((uint)f2bf(vv[ri].y) << 16);
        uint u1 = (uint)f2bf(vv[ri].z) | ((uint)f2bf(vv[ri].w) << 16);
        *(uint2*)&outF16[(size_t)row * 64 + c0] = make_uint2(u0, u1);
        if (cq == 0 && outA0)
            outA0[row] = make_float2(s0[ri] * LOG2E, s0x[ri] * LOG2E);
        if (cq == 1 && outA1)
            outA1[row] = make_float2(s1[ri] * LOG2E, s1x[ri] * LOG2E);
    }
}

// ---------------------------------------------------------------------------
// Mega kernel: segments [C: rel proj | A: target proj | B: mid proj | D: deg]
// ---------------------------------------------------------------------------
__global__ __launch_bounds__(256) void mega_kernel(
    const float* __restrict__ h, const float* __restrict__ W_t, const float* __restrict__ b_t,
    const float* __restrict__ nfeat_mid, const float* __restrict__ W_mid, const float* __restrict__ b_mid,
    const float* __restrict__ efeat_rel, const float* __restrict__ W_rel, const float* __restrict__ b_rel,
    const float* __restrict__ attn_src, const float* __restrict__ attn_dst, const float* __restrict__ attn_edge,
    const int* __restrict__ dst_idx, int* __restrict__ deg,
    float* __restrict__ hp32, unsigned short* __restrict__ hp16,
    unsigned short* __restrict__ mid16, unsigned short* __restrict__ rel16,
    float2* __restrict__ e_src, float2* __restrict__ e_dst,
    float2* __restrict__ em, float2* __restrict__ er,
    int N, int EREL, int E, int nC, int nA, int nB)
{
    __shared__ float Xsh[64 * 68];
    __shared__ float av0sh[64], av1sh[64], bsh[64];
    int b = blockIdx.x;
    if (b < nC) {
        proj_body<32>(b, efeat_rel, W_rel, b_rel, attn_edge, nullptr, 2, EREL,
                      nullptr, rel16, er, nullptr, Xsh, av0sh, av1sh, bsh);
    } else if (b < nC + nA) {
        proj_body<64>(b - nC, h, W_t, b_t, attn_src, attn_dst, 0, N,
                      hp32, hp16, e_src, e_dst, Xsh, av0sh, av1sh, bsh);
    } else if (b < nC + nA + nB) {
        proj_body<64>(b - nC - nA, nfeat_mid, W_mid, b_mid, attn_edge, nullptr, 1, N,
                      nullptr, mid16, em, nullptr, Xsh, av0sh, av1sh, bsh);
    } else {
        int i = (b - nC - nA - nB) * 256 + threadIdx.x;
        if (i < E) atomicAdd(&deg[dst_idx[i]], 1);
    }
}

// ---------------------------------------------------------------------------
__global__ __launch_bounds__(256) void scanA_kernel(
    const int* __restrict__ deg, int* __restrict__ blkSums, int N)
{
    __shared__ int red[256];
    int t = threadIdx.x;
    int base = blockIdx.x * 1024 + t * 4;
    int s = 0;
    if (base + 3 < N) {
        int4 v = *(const int4*)&deg[base];
        s = v.x + v.y + v.z + v.w;
    } else {
        for (int i = 0; i < 4; ++i) if (base + i < N) s += deg[base + i];
    }
    red[t] = s;
    __syncthreads();
    for (int off = 128; off >= 1; off >>= 1) {
        if (t < off) red[t] += red[t + off];
        __syncthreads();
    }
    if (t == 0) blkSums[blockIdx.x] = red[0];
}

// ---------------------------------------------------------------------------
__global__ __launch_bounds__(256) void scanC_kernel(
    const int* __restrict__ deg, const int* __restrict__ blkSums,
    int* __restrict__ row_ptr, int* __restrict__ cursor, int N, int nblk)
{
    __shared__ int sh[256];
    __shared__ int blkOffSh;
    int t = threadIdx.x;
    int blk = blockIdx.x;
    int base = blk * 1024 + t * 4;

    if (t < 64) {
        int s = 0;
        for (int j = t; j < blk; j += 64) s += blkSums[j];
        for (int m = 32; m >= 1; m >>= 1) s += __shfl_xor(s, m, 64);
        if (t == 0) blkOffSh = s;
    }

    int4 v = make_int4(0, 0, 0, 0);
    if (base + 3 < N) v = *(const int4*)&deg[base];
    else {
        if (base < N)     v.x = deg[base];
        if (base + 1 < N) v.y = deg[base + 1];
        if (base + 2 < N) v.z = deg[base + 2];
    }
    int ts = v.x + v.y + v.z + v.w;
    sh[t] = ts;
    __syncthreads();
    for (int off = 1; off < 256; off <<= 1) {
        int val = (t >= off) ? sh[t - off] : 0;
        __syncthreads();
        sh[t] += val;
        __syncthreads();
    }
    int blkOff = blkOffSh;
    int ex = blkOff + ((t == 0) ? 0 : sh[t - 1]);
    int p0 = ex, p1 = ex + v.x, p2 = p1 + v.y, p3 = p2 + v.z;
    if (base < N)     { row_ptr[base]     = p0; cursor[base]     = p0; }
    if (base + 1 < N) { row_ptr[base + 1] = p1; cursor[base + 1] = p1; }
    if (base + 2 < N) { row_ptr[base + 2] = p2; cursor[base + 2] = p2; }
    if (base + 3 < N) { row_ptr[base + 3] = p3; cursor[base + 3] = p3; }
    if (blk == nblk - 1 && t == 255) row_ptr[N] = blkOff + sh[255];
}

// ---------------------------------------------------------------------------
// Fused edge-logit + CSR scatter. One packed 16B record per edge:
//   { src | (hn<<16), he, e_head0_bits, e_head1_bits }  (log2 domain, ±60 clamp)
// ---------------------------------------------------------------------------
__global__ __launch_bounds__(256) void scatter_kernel(
    const int* __restrict__ src, const int* __restrict__ dst,
    const int* __restrict__ hn, const int* __restrict__ he,
    const float2* __restrict__ es, const float2* __restrict__ ed,
    const float2* __restrict__ em, const float2* __restrict__ er,
    int* __restrict__ cursor, uint4* __restrict__ erec, int E)
{
    int i = blockIdx.x * blockDim.x + threadIdx.x;
    if (i >= E) return;
    int s = src[i], d = dst[i], a = hn[i], b = he[i];
    float2 v1 = es[s], v2 = ed[d], v3 = em[a], v4 = er[b];
    float e0 = fminf(fmaxf(v1.x + v2.x + v3.x + v4.x, -60.f), 60.f);
    float e1 = fminf(fmaxf(v1.y + v2.y + v3.y + v4.y, -60.f), 60.f);
    int pos = atomicAdd(&cursor[d], 1);
    erec[pos] = make_uint4((uint)s | ((uint)a << 16), (uint)b,
                           __float_as_uint(e0), __float_as_uint(e1));
}

// ---------------------------------------------------------------------------
// Per-node aggregation, single pass. MLP comes from walking the node's edge
// list as TWO independent half-chains in one loop body (separate accumulator
// sets, no shared registers) -> both halves' 6 loads issue before either
// wait. (R7 lesson: rotation-register pipelines get serialized by the
// VGPR-minimizing scheduler; structural independence does not.)
// ---------------------------------------------------------------------------
__global__ __launch_bounds__(256) void aggregate_kernel(
    const int* __restrict__ row_ptr, const uint4* __restrict__ erec,
    const float* __restrict__ hp32,
    const unsigned short* __restrict__ hp16,
    const unsigned short* __restrict__ mid16,
    const unsigned short* __restrict__ rel16,
    const float* __restrict__ We, const float* __restrict__ be,
    float* __restrict__ out, int N)
{
    __shared__ float WeSh[64 * 32];
    __shared__ float ft2sh[4][128];
    int t = threadIdx.x;
    for (int i = t; i < 64 * 32; i += 256) WeSh[i] = We[i];
    __syncthreads();

    int wave = t >> 6, lane = t & 63;
    int head = lane >> 5, dj = lane & 31;
    int n = blockIdx.x * 4 + wave;
    bool valid = n < N;
    int nn = valid ? n : 0;

    int start = row_ptr[nn], end = row_ptr[nn + 1];
    int cnt = end - start;
    int lenA = cnt >> 1;
    int midp = start + lenA;

    bool isrel = lane >= 32;
    int l31 = lane & 31;
    bool h1w = ((lane >> 4) & 1) != 0;
    const uint* tab32 = (const uint*)(isrel ? rel16 : mid16);

    float rstcA = 0.f, fxA = 0.f, fyA = 0.f, den0A = 0.f, den1A = 0.f;
    float rstcB = 0.f, fxB = 0.f, fyB = 0.f, den0B = 0.f, den1B = 0.f;

#pragma unroll 2
    for (int k = 0; k < lenA; ++k) {
        uint4 rA = erec[start + k];
        uint4 rB = erec[midp + k];
        uint huA = (uint)hp16[((rA.x & 0xffffu) << 6) | (uint)lane];
        uint huB = (uint)hp16[((rB.x & 0xffffu) << 6) | (uint)lane];
        uint pvA = tab32[((isrel ? rA.y : (rA.x >> 16)) << 5) | (uint)l31];
        uint pvB = tab32[((isrel ? rB.y : (rB.x >> 16)) << 5) | (uint)l31];

        float a0A = __builtin_amdgcn_exp2f(__uint_as_float(rA.z));
        float a1A = __builtin_amdgcn_exp2f(__uint_as_float(rA.w));
        den0A += a0A; den1A += a1A;
        rstcA += bf16u(huA) * (head ? a1A : a0A);
        float wA = h1w ? a1A : a0A;
        fxA += bf16_lo(pvA) * wA;
        fyA += bf16_hi(pvA) * wA;

        float a0B = __builtin_amdgcn_exp2f(__uint_as_float(rB.z));
        float a1B = __builtin_amdgcn_exp2f(__uint_as_float(rB.w));
        den0B += a0B; den1B += a1B;
        rstcB += bf16u(huB) * (head ? a1B : a0B);
        float wB = h1w ? a1B : a0B;
        fxB += bf16_lo(pvB) * wB;
        fyB += bf16_hi(pvB) * wB;
    }
    if (cnt & 1) {
        uint4 rB = erec[end - 1];
        uint huB = (uint)hp16[((rB.x & 0xffffu) << 6) | (uint)lane];
        uint pvB = tab32[((isrel ? rB.y : (rB.x >> 16)) << 5) | (uint)l31];
        float a0B = __builtin_amdgcn_exp2f(__uint_as_float(rB.z));
        float a1B = __builtin_amdgcn_exp2f(__uint_as_float(rB.w));
        den0B += a0B; den1B += a1B;
        rstcB += bf16u(huB) * (head ? a1B : a0B);
        float wB = h1w ? a1B : a0B;
        fxB += bf16_lo(pvB) * wB;
        fyB += bf16_hi(pvB) * wB;
    }

    float den0 = den0A + den0B, den1 = den1A + den1B;
    float rstc = rstcA + rstcB, fx = fxA + fxB, fy = fyA + fyB;

    float inv0 = den0 > 0.f ? 1.f / den0 : 0.f;
    float inv1 = den1 > 0.f ? 1.f / den1 : 0.f;
    rstc *= head ? inv1 : inv0;
    float invf = h1w ? inv1 : inv0;

    int slotbase;
    if (lane < 16)      slotbase = 2 * lane;
    else if (lane < 32) slotbase = 2 * lane + 32;
    else if (lane < 48) slotbase = 2 * lane - 32;
    else                slotbase = 2 * lane;
    ft2sh[wave][slotbase]     = fx * invf;
    ft2sh[wave][slotbase + 1] = fy * invf;

    // wave-local LDS fence (ft2sh region is per-wave)
    __builtin_amdgcn_sched_barrier(0);
    asm volatile("s_waitcnt lgkmcnt(0)" ::: "memory");
    __builtin_amdgcn_sched_barrier(0);

    float fc = be[dj];
#pragma unroll 8
    for (int dd = 0; dd < 64; ++dd)
        fc += ft2sh[wave][head * 64 + dd] * WeSh[dd * 32 + dj];

    float val = rstc + fc + hp32[(uint)nn * 64 + lane];
    val = fmaxf(val, 0.f);

    float ss = val * val;
    for (int m = 32; m >= 1; m >>= 1) ss += __shfl_xor(ss, m, 64);
    float invn = 1.f / fmaxf(sqrtf(ss), 1e-12f);
    if (valid) out[(uint)nn * 64 + lane] = val * invn;
}

// ---------------------------------------------------------------------------
extern "C" void kernel_launch(void* const* d_in, const int* in_sizes, int n_in,
                              void* d_out, int out_size, void* d_ws, size_t ws_size,
                              hipStream_t stream)
{
    const float* h         = (const float*)d_in[0];
    const float* W_t       = (const float*)d_in[1];
    const float* b_t       = (const float*)d_in[2];
    const float* nfeat_mid = (const float*)d_in[3];
    const float* W_mid     = (const float*)d_in[4];
    const float* b_mid     = (const float*)d_in[5];
    const float* efeat_rel = (const float*)d_in[6];
    const float* W_rel     = (const float*)d_in[7];
    const float* b_rel     = (const float*)d_in[8];
    const float* attn_src  = (const float*)d_in[9];
    const float* attn_dst  = (const float*)d_in[10];
    const float* attn_edge = (const float*)d_in[11];
    const float* W_edge    = (const float*)d_in[12];
    const float* b_edge    = (const float*)d_in[13];
    const int* src_idx     = (const int*)d_in[14];
    const int* dst_idx     = (const int*)d_in[15];
    const int* hn          = (const int*)d_in[16];
    const int* he          = (const int*)d_in[17];
    float* out = (float*)d_out;

    const int N    = in_sizes[0] / 64;
    const int EREL = in_sizes[6] / 32;
    const int E    = in_sizes[14];

    char* ws = (char*)d_ws;
    auto alloc = [&](size_t bytes) {
        void* p = (void*)ws;
        ws += (bytes + 255) & ~(size_t)255;
        return p;
    };
    float* hp32           = (float*)alloc((size_t)N * 64 * 4);
    unsigned short* hp16  = (unsigned short*)alloc((size_t)N * 64 * 2);
    unsigned short* mid16 = (unsigned short*)alloc((size_t)N * 64 * 2);
    unsigned short* rel16 = (unsigned short*)alloc((size_t)EREL * 64 * 2);
    float2* e_src  = (float2*)alloc((size_t)N * 8);
    float2* e_dst  = (float2*)alloc((size_t)N * 8);
    float2* em     = (float2*)alloc((size_t)N * 8);
    float2* er     = (float2*)alloc((size_t)EREL * 8);
    int* deg       = (int*)alloc((size_t)N * 4);
    int* row_ptr   = (int*)alloc((size_t)(N + 1) * 4);
    int* cursor    = (int*)alloc((size_t)N * 4);
    int* blkSums   = (int*)alloc((size_t)64 * 4);
    uint4* erec    = (uint4*)alloc((size_t)E * 16);

    hipMemsetAsync(deg, 0, (size_t)N * 4, stream);

    int nA = (N + 63) / 64;
    int nB = nA;
    int nC = (EREL + 63) / 64;
    int nD = (E + 255) / 256;
    mega_kernel<<<nC + nA + nB + nD, 256, 0, stream>>>(
        h, W_t, b_t, nfeat_mid, W_mid, b_mid, efeat_rel, W_rel, b_rel,
        attn_src, attn_dst, attn_edge, dst_idx, deg,
        hp32, hp16, mid16, rel16, e_src, e_dst, em, er,
        N, EREL, E, nC, nA, nB);

    int nblk = (N + 1023) / 1024;
    scanA_kernel<<<nblk, 256, 0, stream>>>(deg, blkSums, N);
    scanC_kernel<<<nblk, 256, 0, stream>>>(deg, blkSums, row_ptr, cursor, N, nblk);

    scatter_kernel<<<(E + 255) / 256, 256, 0, stream>>>(
        src_idx, dst_idx, hn, he, e_src, e_dst, em, er, cursor, erec, E);

    aggregate_kernel<<<(N + 3) / 4, 256, 0, stream>>>(
        row_ptr, erec, hp32, hp16, mid16, rel16, W_edge, b_edge, out, N);
}

// Round 9
// 282.263 us; speedup vs baseline: 1.1460x; 1.0695x over previous
//
#include <hip/hip_runtime.h>

typedef unsigned int uint;
typedef float f32x4 __attribute__((ext_vector_type(4)));
typedef short short8 __attribute__((ext_vector_type(8)));
#define LOG2E 1.4426950408889634f

__device__ __forceinline__ float bf16_lo(uint v) { return __uint_as_float(v << 16); }
__device__ __forceinline__ float bf16_hi(uint v) { return __uint_as_float(v & 0xffff0000u); }
__device__ __forceinline__ unsigned short f2bf(float f) {
    uint u = __float_as_uint(f);
    return (unsigned short)((u + 0x7fffu + ((u >> 16) & 1u)) >> 16);  // RNE
}
__device__ __forceinline__ float bf16u(uint s) {
    return __uint_as_float(s << 16);
}

// ---------------------------------------------------------------------------
// MFMA projection: out[row][c] = X[row,:K] @ W[:K,c] + b[c], 64 rows/block.
// X and W^T staged as bf16 in LDS (~19KB total -> 8 blocks/CU). Wave w owns
// rows 16w..16w+15 as 4 col-tiles of 16x16 via v_mfma_f32_16x16x32_bf16.
// A frag: lane l -> Xbf[16w + (l&15)][ks*32 + (l>>4)*8 ..+7]
// B frag: lane l -> WT [16c + (l&15)][ks*32 + (l>>4)*8 ..+7]   (WT = W^T)
// C/D:    col = 16c + (l&15), row_local = 4*(l>>4) + reg       [m89-verified]
// Attention sums pre-scaled by LOG2E (downstream logits in log2 domain).
// ---------------------------------------------------------------------------
template<int K>
__device__ __forceinline__ void proj_mfma(
    int blk, const float* __restrict__ X, const float* __restrict__ W,
    const float* __restrict__ bias, const float* __restrict__ avec0,
    const float* __restrict__ avec1, int mode, int nrows,
    unsigned short* __restrict__ outF16,
    float2* __restrict__ outA0, float2* __restrict__ outA1,
    unsigned short* Xbf, unsigned short* WT,
    float* av0sh, float* av1sh, float* bsh)
{
    constexpr int KP = K + 8;          // padded bf16 row stride (16B-aligned)
    int t = threadIdx.x;

    if (t < 64) {
        int head = t >> 5, d = t & 31;
        int aidx = (mode == 0) ? t : (mode == 1 ? head * 64 + d : head * 64 + 32 + d);
        av0sh[t] = avec0 ? avec0[aidx] : 0.f;
        av1sh[t] = avec1 ? avec1[aidx] : 0.f;
        bsh[t] = bias[t];
    }

    int base = blk * 64;
    constexpr int FP4R = K / 4;        // float4 per X row
    const float4* X4 = (const float4*)X;
    for (int f = t; f < 64 * FP4R; f += 256) {
        int row = f / FP4R, c4 = f % FP4R;
        int gr = base + row; if (gr >= nrows) gr = nrows - 1;
        float4 v = X4[(size_t)gr * FP4R + c4];
        uint2 u;
        u.x = (uint)f2bf(v.x) | ((uint)f2bf(v.y) << 16);
        u.y = (uint)f2bf(v.z) | ((uint)f2bf(v.w) << 16);
        *(uint2*)&Xbf[row * KP + c4 * 4] = u;
    }
    // W [K][64] f32 -> WT [64][KP] bf16 (transpose)
    const float4* W4 = (const float4*)W;
    for (int f = t; f < K * 16; f += 256) {
        int k = f >> 4, c4 = (f & 15) * 4;
        float4 v = W4[f];
        WT[(c4 + 0) * KP + k] = f2bf(v.x);
        WT[(c4 + 1) * KP + k] = f2bf(v.y);
        WT[(c4 + 2) * KP + k] = f2bf(v.z);
        WT[(c4 + 3) * KP + k] = f2bf(v.w);
    }
    __syncthreads();

    int w = t >> 6, l = t & 63;
    int l15 = l & 15, kg = l >> 4;

    short8 a[K / 32];
#pragma unroll
    for (int ks = 0; ks < K / 32; ++ks)
        a[ks] = *(const short8*)&Xbf[(16 * w + l15) * KP + ks * 32 + kg * 8];

    f32x4 acc[4];
#pragma unroll
    for (int c = 0; c < 4; ++c) {
        acc[c] = (f32x4){0.f, 0.f, 0.f, 0.f};
#pragma unroll
        for (int ks = 0; ks < K / 32; ++ks) {
            short8 b = *(const short8*)&WT[(16 * c + l15) * KP + ks * 32 + kg * 8];
            acc[c] = __builtin_amdgcn_mfma_f32_16x16x32_bf16(a[ks], b, acc[c], 0, 0, 0);
        }
    }

    // epilogue: per reg r the lane covers row 16w+4kg+r, cols {16c + l15}
#pragma unroll
    for (int r = 0; r < 4; ++r) {
        int grow = base + 16 * w + 4 * kg + r;
        bool rok = grow < nrows;
        float p00 = 0.f, p01 = 0.f, p10 = 0.f, p11 = 0.f;
#pragma unroll
        for (int c = 0; c < 4; ++c) {
            int col = 16 * c + l15;
            float val = acc[c][r] + bsh[col];
            if (rok) outF16[(size_t)grow * 64 + col] = f2bf(val);
            float rl = fmaxf(val, 0.f);
            float q0 = av0sh[col] * rl, q1 = av1sh[col] * rl;
            if (c < 2) { p00 += q0; p10 += q1; }   // head 0 (cols 0..31)
            else       { p01 += q0; p11 += q1; }   // head 1 (cols 32..63)
        }
        // reduce across the 16 lanes sharing kg (bits 0..3 of lane)
        p00 += __shfl_xor(p00, 1, 64); p00 += __shfl_xor(p00, 2, 64);
        p00 += __shfl_xor(p00, 4, 64); p00 += __shfl_xor(p00, 8, 64);
        p01 += __shfl_xor(p01, 1, 64); p01 += __shfl_xor(p01, 2, 64);
        p01 += __shfl_xor(p01, 4, 64); p01 += __shfl_xor(p01, 8, 64);
        p10 += __shfl_xor(p10, 1, 64); p10 += __shfl_xor(p10, 2, 64);
        p10 += __shfl_xor(p10, 4, 64); p10 += __shfl_xor(p10, 8, 64);
        p11 += __shfl_xor(p11, 1, 64); p11 += __shfl_xor(p11, 2, 64);
        p11 += __shfl_xor(p11, 4, 64); p11 += __shfl_xor(p11, 8, 64);
        if (l15 == 0 && rok) {
            outA0[grow] = make_float2(p00 * LOG2E, p01 * LOG2E);
            if (outA1) outA1[grow] = make_float2(p10 * LOG2E, p11 * LOG2E);
        }
    }
}

// ---------------------------------------------------------------------------
// Mega kernel: segments [C: rel proj | A: target proj | B: mid proj | D: deg]
// ---------------------------------------------------------------------------
__global__ __launch_bounds__(256) void mega_kernel(
    const float* __restrict__ h, const float* __restrict__ W_t, const float* __restrict__ b_t,
    const float* __restrict__ nfeat_mid, const float* __restrict__ W_mid, const float* __restrict__ b_mid,
    const float* __restrict__ efeat_rel, const float* __restrict__ W_rel, const float* __restrict__ b_rel,
    const float* __restrict__ attn_src, const float* __restrict__ attn_dst, const float* __restrict__ attn_edge,
    const int* __restrict__ dst_idx, int* __restrict__ deg,
    unsigned short* __restrict__ hp16,
    unsigned short* __restrict__ mid16, unsigned short* __restrict__ rel16,
    float2* __restrict__ e_src, float2* __restrict__ e_dst,
    float2* __restrict__ em, float2* __restrict__ er,
    int N, int EREL, int E, int nC, int nA, int nB)
{
    __shared__ unsigned short Xbf[64 * 72];
    __shared__ unsigned short WT[64 * 72];
    __shared__ float av0sh[64], av1sh[64], bsh[64];
    int b = blockIdx.x;
    if (b < nC) {
        proj_mfma<32>(b, efeat_rel, W_rel, b_rel, attn_edge, nullptr, 2, EREL,
                      rel16, er, nullptr, Xbf, WT, av0sh, av1sh, bsh);
    } else if (b < nC + nA) {
        proj_mfma<64>(b - nC, h, W_t, b_t, attn_src, attn_dst, 0, N,
                      hp16, e_src, e_dst, Xbf, WT, av0sh, av1sh, bsh);
    } else if (b < nC + nA + nB) {
        proj_mfma<64>(b - nC - nA, nfeat_mid, W_mid, b_mid, attn_edge, nullptr, 1, N,
                      mid16, em, nullptr, Xbf, WT, av0sh, av1sh, bsh);
    } else {
        int i = (b - nC - nA - nB) * 256 + threadIdx.x;
        if (i < E) atomicAdd(&deg[dst_idx[i]], 1);
    }
}

// ---------------------------------------------------------------------------
__global__ __launch_bounds__(256) void scanA_kernel(
    const int* __restrict__ deg, int* __restrict__ blkSums, int N)
{
    __shared__ int red[256];
    int t = threadIdx.x;
    int base = blockIdx.x * 1024 + t * 4;
    int s = 0;
    if (base + 3 < N) {
        int4 v = *(const int4*)&deg[base];
        s = v.x + v.y + v.z + v.w;
    } else {
        for (int i = 0; i < 4; ++i) if (base + i < N) s += deg[base + i];
    }
    red[t] = s;
    __syncthreads();
    for (int off = 128; off >= 1; off >>= 1) {
        if (t < off) red[t] += red[t + off];
        __syncthreads();
    }
    if (t == 0) blkSums[blockIdx.x] = red[0];
}

// ---------------------------------------------------------------------------
__global__ __launch_bounds__(256) void scanC_kernel(
    const int* __restrict__ deg, const int* __restrict__ blkSums,
    int* __restrict__ row_ptr, int* __restrict__ cursor, int N, int nblk)
{
    __shared__ int sh[256];
    __shared__ int blkOffSh;
    int t = threadIdx.x;
    int blk = blockIdx.x;
    int base = blk * 1024 + t * 4;

    if (t < 64) {
        int s = 0;
        for (int j = t; j < blk; j += 64) s += blkSums[j];
        for (int m = 32; m >= 1; m >>= 1) s += __shfl_xor(s, m, 64);
        if (t == 0) blkOffSh = s;
    }

    int4 v = make_int4(0, 0, 0, 0);
    if (base + 3 < N) v = *(const int4*)&deg[base];
    else {
        if (base < N)     v.x = deg[base];
        if (base + 1 < N) v.y = deg[base + 1];
        if (base + 2 < N) v.z = deg[base + 2];
    }
    int ts = v.x + v.y + v.z + v.w;
    sh[t] = ts;
    __syncthreads();
    for (int off = 1; off < 256; off <<= 1) {
        int val = (t >= off) ? sh[t - off] : 0;
        __syncthreads();
        sh[t] += val;
        __syncthreads();
    }
    int blkOff = blkOffSh;
    int ex = blkOff + ((t == 0) ? 0 : sh[t - 1]);
    int p0 = ex, p1 = ex + v.x, p2 = p1 + v.y, p3 = p2 + v.z;
    if (base < N)     { row_ptr[base]     = p0; cursor[base]     = p0; }
    if (base + 1 < N) { row_ptr[base + 1] = p1; cursor[base + 1] = p1; }
    if (base + 2 < N) { row_ptr[base + 2] = p2; cursor[base + 2] = p2; }
    if (base + 3 < N) { row_ptr[base + 3] = p3; cursor[base + 3] = p3; }
    if (blk == nblk - 1 && t == 255) row_ptr[N] = blkOff + sh[255];
}

// ---------------------------------------------------------------------------
// Fused edge-logit + CSR scatter. One packed 16B record per edge:
//   { src | (hn<<16), he, e_head0_bits, e_head1_bits }  (log2 domain, ±60 clamp)
// ---------------------------------------------------------------------------
__global__ __launch_bounds__(256) void scatter_kernel(
    const int* __restrict__ src, const int* __restrict__ dst,
    const int* __restrict__ hn, const int* __restrict__ he,
    const float2* __restrict__ es, const float2* __restrict__ ed,
    const float2* __restrict__ em, const float2* __restrict__ er,
    int* __restrict__ cursor, uint4* __restrict__ erec, int E)
{
    int i = blockIdx.x * blockDim.x + threadIdx.x;
    if (i >= E) return;
    int s = src[i], d = dst[i], a = hn[i], b = he[i];
    float2 v1 = es[s], v2 = ed[d], v3 = em[a], v4 = er[b];
    float e0 = fminf(fmaxf(v1.x + v2.x + v3.x + v4.x, -60.f), 60.f);
    float e1 = fminf(fmaxf(v1.y + v2.y + v3.y + v4.y, -60.f), 60.f);
    int pos = atomicAdd(&cursor[d], 1);
    erec[pos] = make_uint4((uint)s | ((uint)a << 16), (uint)b,
                           __float_as_uint(e0), __float_as_uint(e1));
}

// ---------------------------------------------------------------------------
// Per-node aggregation, single pass, two independent half-chains for MLP
// (R7/R8 lesson: structural independence, not rotation registers).
// ---------------------------------------------------------------------------
__global__ __launch_bounds__(256) void aggregate_kernel(
    const int* __restrict__ row_ptr, const uint4* __restrict__ erec,
    const unsigned short* __restrict__ hp16,
    const unsigned short* __restrict__ mid16,
    const unsigned short* __restrict__ rel16,
    const float* __restrict__ We, const float* __restrict__ be,
    float* __restrict__ out, int N)
{
    __shared__ float WeSh[64 * 32];
    __shared__ float ft2sh[4][128];
    int t = threadIdx.x;
    for (int i = t; i < 64 * 32; i += 256) WeSh[i] = We[i];
    __syncthreads();

    int wave = t >> 6, lane = t & 63;
    int head = lane >> 5, dj = lane & 31;
    int n = blockIdx.x * 4 + wave;
    bool valid = n < N;
    int nn = valid ? n : 0;

    int start = row_ptr[nn], end = row_ptr[nn + 1];
    int cnt = end - start;
    int lenA = cnt >> 1;
    int midp = start + lenA;

    bool isrel = lane >= 32;
    int l31 = lane & 31;
    bool h1w = ((lane >> 4) & 1) != 0;
    const uint* tab32 = (const uint*)(isrel ? rel16 : mid16);

    float rstcA = 0.f, fxA = 0.f, fyA = 0.f, den0A = 0.f, den1A = 0.f;
    float rstcB = 0.f, fxB = 0.f, fyB = 0.f, den0B = 0.f, den1B = 0.f;

#pragma unroll 2
    for (int k = 0; k < lenA; ++k) {
        uint4 rA = erec[start + k];
        uint4 rB = erec[midp + k];
        uint huA = (uint)hp16[((rA.x & 0xffffu) << 6) | (uint)lane];
        uint huB = (uint)hp16[((rB.x & 0xffffu) << 6) | (uint)lane];
        uint pvA = tab32[((isrel ? rA.y : (rA.x >> 16)) << 5) | (uint)l31];
        uint pvB = tab32[((isrel ? rB.y : (rB.x >> 16)) << 5) | (uint)l31];

        float a0A = __builtin_amdgcn_exp2f(__uint_as_float(rA.z));
        float a1A = __builtin_amdgcn_exp2f(__uint_as_float(rA.w));
        den0A += a0A; den1A += a1A;
        rstcA += bf16u(huA) * (head ? a1A : a0A);
        float wA = h1w ? a1A : a0A;
        fxA += bf16_lo(pvA) * wA;
        fyA += bf16_hi(pvA) * wA;

        float a0B = __builtin_amdgcn_exp2f(__uint_as_float(rB.z));
        float a1B = __builtin_amdgcn_exp2f(__uint_as_float(rB.w));
        den0B += a0B; den1B += a1B;
        rstcB += bf16u(huB) * (head ? a1B : a0B);
        float wB = h1w ? a1B : a0B;
        fxB += bf16_lo(pvB) * wB;
        fyB += bf16_hi(pvB) * wB;
    }
    if (cnt & 1) {
        uint4 rB = erec[end - 1];
        uint huB = (uint)hp16[((rB.x & 0xffffu) << 6) | (uint)lane];
        uint pvB = tab32[((isrel ? rB.y : (rB.x >> 16)) << 5) | (uint)l31];
        float a0B = __builtin_amdgcn_exp2f(__uint_as_float(rB.z));
        float a1B = __builtin_amdgcn_exp2f(__uint_as_float(rB.w));
        den0B += a0B; den1B += a1B;
        rstcB += bf16u(huB) * (head ? a1B : a0B);
        float wB = h1w ? a1B : a0B;
        fxB += bf16_lo(pvB) * wB;
        fyB += bf16_hi(pvB) * wB;
    }

    float den0 = den0A + den0B, den1 = den1A + den1B;
    float rstc = rstcA + rstcB, fx = fxA + fxB, fy = fyA + fyB;

    float inv0 = den0 > 0.f ? 1.f / den0 : 0.f;
    float inv1 = den1 > 0.f ? 1.f / den1 : 0.f;
    rstc *= head ? inv1 : inv0;
    float invf = h1w ? inv1 : inv0;

    int slotbase;
    if (lane < 16)      slotbase = 2 * lane;
    else if (lane < 32) slotbase = 2 * lane + 32;
    else if (lane < 48) slotbase = 2 * lane - 32;
    else                slotbase = 2 * lane;
    ft2sh[wave][slotbase]     = fx * invf;
    ft2sh[wave][slotbase + 1] = fy * invf;

    // wave-local LDS fence (ft2sh region is per-wave)
    __builtin_amdgcn_sched_barrier(0);
    asm volatile("s_waitcnt lgkmcnt(0)" ::: "memory");
    __builtin_amdgcn_sched_barrier(0);

    float fc = be[dj];
#pragma unroll 8
    for (int dd = 0; dd < 64; ++dd)
        fc += ft2sh[wave][head * 64 + dd] * WeSh[dd * 32 + dj];

    float val = rstc + fc + bf16u((uint)hp16[(uint)nn * 64 + (uint)lane]);
    val = fmaxf(val, 0.f);

    float ss = val * val;
    for (int m = 32; m >= 1; m >>= 1) ss += __shfl_xor(ss, m, 64);
    float invn = 1.f / fmaxf(sqrtf(ss), 1e-12f);
    if (valid) out[(uint)nn * 64 + lane] = val * invn;
}

// ---------------------------------------------------------------------------
extern "C" void kernel_launch(void* const* d_in, const int* in_sizes, int n_in,
                              void* d_out, int out_size, void* d_ws, size_t ws_size,
                              hipStream_t stream)
{
    const float* h         = (const float*)d_in[0];
    const float* W_t       = (const float*)d_in[1];
    const float* b_t       = (const float*)d_in[2];
    const float* nfeat_mid = (const float*)d_in[3];
    const float* W_mid     = (const float*)d_in[4];
    const float* b_mid     = (const float*)d_in[5];
    const float* efeat_rel = (const float*)d_in[6];
    const float* W_rel     = (const float*)d_in[7];
    const float* b_rel     = (const float*)d_in[8];
    const float* attn_src  = (const float*)d_in[9];
    const float* attn_dst  = (const float*)d_in[10];
    const float* attn_edge = (const float*)d_in[11];
    const float* W_edge    = (const float*)d_in[12];
    const float* b_edge    = (const float*)d_in[13];
    const int* src_idx     = (const int*)d_in[14];
    const int* dst_idx     = (const int*)d_in[15];
    const int* hn          = (const int*)d_in[16];
    const int* he          = (const int*)d_in[17];
    float* out = (float*)d_out;

    const int N    = in_sizes[0] / 64;
    const int EREL = in_sizes[6] / 32;
    const int E    = in_sizes[14];

    char* ws = (char*)d_ws;
    auto alloc = [&](size_t bytes) {
        void* p = (void*)ws;
        ws += (bytes + 255) & ~(size_t)255;
        return p;
    };
    unsigned short* hp16  = (unsigned short*)alloc((size_t)N * 64 * 2);
    unsigned short* mid16 = (unsigned short*)alloc((size_t)N * 64 * 2);
    unsigned short* rel16 = (unsigned short*)alloc((size_t)EREL * 64 * 2);
    float2* e_src  = (float2*)alloc((size_t)N * 8);
    float2* e_dst  = (float2*)alloc((size_t)N * 8);
    float2* em     = (float2*)alloc((size_t)N * 8);
    float2* er     = (float2*)alloc((size_t)EREL * 8);
    int* deg       = (int*)alloc((size_t)N * 4);
    int* row_ptr   = (int*)alloc((size_t)(N + 1) * 4);
    int* cursor    = (int*)alloc((size_t)N * 4);
    int* blkSums   = (int*)alloc((size_t)64 * 4);
    uint4* erec    = (uint4*)alloc((size_t)E * 16);

    hipMemsetAsync(deg, 0, (size_t)N * 4, stream);

    int nA = (N + 63) / 64;
    int nB = nA;
    int nC = (EREL + 63) / 64;
    int nD = (E + 255) / 256;
    mega_kernel<<<nC + nA + nB + nD, 256, 0, stream>>>(
        h, W_t, b_t, nfeat_mid, W_mid, b_mid, efeat_rel, W_rel, b_rel,
        attn_src, attn_dst, attn_edge, dst_idx, deg,
        hp16, mid16, rel16, e_src, e_dst, em, er,
        N, EREL, E, nC, nA, nB);

    int nblk = (N + 1023) / 1024;
    scanA_kernel<<<nblk, 256, 0, stream>>>(deg, blkSums, N);
    scanC_kernel<<<nblk, 256, 0, stream>>>(deg, blkSums, row_ptr, cursor, N, nblk);

    scatter_kernel<<<(E + 255) / 256, 256, 0, stream>>>(
        src_idx, dst_idx, hn, he, e_src, e_dst, em, er, cursor, erec, E);

    aggregate_kernel<<<(N + 3) / 4, 256, 0, stream>>>(
        row_ptr, erec, hp16, mid16, rel16, W_edge, b_edge, out, N);
}

// Round 10
// 281.048 us; speedup vs baseline: 1.1510x; 1.0043x over previous
//
#include <hip/hip_runtime.h>

typedef unsigned int uint;
typedef float f32x4 __attribute__((ext_vector_type(4)));
typedef short short8 __attribute__((ext_vector_type(8)));
#define LOG2E 1.4426950408889634f

__device__ __forceinline__ float bf16_lo(uint v) { return __uint_as_float(v << 16); }
__device__ __forceinline__ float bf16_hi(uint v) { return __uint_as_float(v & 0xffff0000u); }
__device__ __forceinline__ unsigned short f2bf(float f) {
    uint u = __float_as_uint(f);
    return (unsigned short)((u + 0x7fffu + ((u >> 16) & 1u)) >> 16);  // RNE
}
__device__ __forceinline__ float bf16u(uint s) {
    return __uint_as_float(s << 16);
}

// ---------------------------------------------------------------------------
// MFMA projection (R9-verified): out = X@W + b, 64 rows/block, bf16 LDS
// staging, v_mfma_f32_16x16x32_bf16, attention sums pre-scaled by LOG2E.
// ---------------------------------------------------------------------------
template<int K>
__device__ __forceinline__ void proj_mfma(
    int blk, const float* __restrict__ X, const float* __restrict__ W,
    const float* __restrict__ bias, const float* __restrict__ avec0,
    const float* __restrict__ avec1, int mode, int nrows,
    unsigned short* __restrict__ outF16,
    float2* __restrict__ outA0, float2* __restrict__ outA1,
    unsigned short* Xbf, unsigned short* WT,
    float* av0sh, float* av1sh, float* bsh)
{
    constexpr int KP = K + 8;
    int t = threadIdx.x;

    if (t < 64) {
        int head = t >> 5, d = t & 31;
        int aidx = (mode == 0) ? t : (mode == 1 ? head * 64 + d : head * 64 + 32 + d);
        av0sh[t] = avec0 ? avec0[aidx] : 0.f;
        av1sh[t] = avec1 ? avec1[aidx] : 0.f;
        bsh[t] = bias[t];
    }

    int base = blk * 64;
    constexpr int FP4R = K / 4;
    const float4* X4 = (const float4*)X;
    for (int f = t; f < 64 * FP4R; f += 256) {
        int row = f / FP4R, c4 = f % FP4R;
        int gr = base + row; if (gr >= nrows) gr = nrows - 1;
        float4 v = X4[(size_t)gr * FP4R + c4];
        uint2 u;
        u.x = (uint)f2bf(v.x) | ((uint)f2bf(v.y) << 16);
        u.y = (uint)f2bf(v.z) | ((uint)f2bf(v.w) << 16);
        *(uint2*)&Xbf[row * KP + c4 * 4] = u;
    }
    const float4* W4 = (const float4*)W;
    for (int f = t; f < K * 16; f += 256) {
        int k = f >> 4, c4 = (f & 15) * 4;
        float4 v = W4[f];
        WT[(c4 + 0) * KP + k] = f2bf(v.x);
        WT[(c4 + 1) * KP + k] = f2bf(v.y);
        WT[(c4 + 2) * KP + k] = f2bf(v.z);
        WT[(c4 + 3) * KP + k] = f2bf(v.w);
    }
    __syncthreads();

    int w = t >> 6, l = t & 63;
    int l15 = l & 15, kg = l >> 4;

    short8 a[K / 32];
#pragma unroll
    for (int ks = 0; ks < K / 32; ++ks)
        a[ks] = *(const short8*)&Xbf[(16 * w + l15) * KP + ks * 32 + kg * 8];

    f32x4 acc[4];
#pragma unroll
    for (int c = 0; c < 4; ++c) {
        acc[c] = (f32x4){0.f, 0.f, 0.f, 0.f};
#pragma unroll
        for (int ks = 0; ks < K / 32; ++ks) {
            short8 b = *(const short8*)&WT[(16 * c + l15) * KP + ks * 32 + kg * 8];
            acc[c] = __builtin_amdgcn_mfma_f32_16x16x32_bf16(a[ks], b, acc[c], 0, 0, 0);
        }
    }

#pragma unroll
    for (int r = 0; r < 4; ++r) {
        int grow = base + 16 * w + 4 * kg + r;
        bool rok = grow < nrows;
        float p00 = 0.f, p01 = 0.f, p10 = 0.f, p11 = 0.f;
#pragma unroll
        for (int c = 0; c < 4; ++c) {
            int col = 16 * c + l15;
            float val = acc[c][r] + bsh[col];
            if (rok) outF16[(size_t)grow * 64 + col] = f2bf(val);
            float rl = fmaxf(val, 0.f);
            float q0 = av0sh[col] * rl, q1 = av1sh[col] * rl;
            if (c < 2) { p00 += q0; p10 += q1; }
            else       { p01 += q0; p11 += q1; }
        }
        p00 += __shfl_xor(p00, 1, 64); p00 += __shfl_xor(p00, 2, 64);
        p00 += __shfl_xor(p00, 4, 64); p00 += __shfl_xor(p00, 8, 64);
        p01 += __shfl_xor(p01, 1, 64); p01 += __shfl_xor(p01, 2, 64);
        p01 += __shfl_xor(p01, 4, 64); p01 += __shfl_xor(p01, 8, 64);
        p10 += __shfl_xor(p10, 1, 64); p10 += __shfl_xor(p10, 2, 64);
        p10 += __shfl_xor(p10, 4, 64); p10 += __shfl_xor(p10, 8, 64);
        p11 += __shfl_xor(p11, 1, 64); p11 += __shfl_xor(p11, 2, 64);
        p11 += __shfl_xor(p11, 4, 64); p11 += __shfl_xor(p11, 8, 64);
        if (l15 == 0 && rok) {
            outA0[grow] = make_float2(p00 * LOG2E, p01 * LOG2E);
            if (outA1) outA1[grow] = make_float2(p10 * LOG2E, p11 * LOG2E);
        }
    }
}

// ---------------------------------------------------------------------------
// Mega kernel: [C: rel proj | A: target proj | B: mid proj | D: deg]
// mid/rel bf16 outputs go into ONE combined table mr16 (mid rows 0..N-1,
// rel rows N..N+EREL-1) so aggregate gets a uniform base pointer.
// ---------------------------------------------------------------------------
__global__ __launch_bounds__(256) void mega_kernel(
    const float* __restrict__ h, const float* __restrict__ W_t, const float* __restrict__ b_t,
    const float* __restrict__ nfeat_mid, const float* __restrict__ W_mid, const float* __restrict__ b_mid,
    const float* __restrict__ efeat_rel, const float* __restrict__ W_rel, const float* __restrict__ b_rel,
    const float* __restrict__ attn_src, const float* __restrict__ attn_dst, const float* __restrict__ attn_edge,
    const int* __restrict__ dst_idx, int* __restrict__ deg,
    unsigned short* __restrict__ hp16, unsigned short* __restrict__ mr16,
    float2* __restrict__ e_src, float2* __restrict__ e_dst,
    float2* __restrict__ em, float2* __restrict__ er,
    int N, int EREL, int E, int nC, int nA, int nB)
{
    __shared__ unsigned short Xbf[64 * 72];
    __shared__ unsigned short WT[64 * 72];
    __shared__ float av0sh[64], av1sh[64], bsh[64];
    int b = blockIdx.x;
    if (b < nC) {
        proj_mfma<32>(b, efeat_rel, W_rel, b_rel, attn_edge, nullptr, 2, EREL,
                      mr16 + (size_t)N * 64, er, nullptr, Xbf, WT, av0sh, av1sh, bsh);
    } else if (b < nC + nA) {
        proj_mfma<64>(b - nC, h, W_t, b_t, attn_src, attn_dst, 0, N,
                      hp16, e_src, e_dst, Xbf, WT, av0sh, av1sh, bsh);
    } else if (b < nC + nA + nB) {
        proj_mfma<64>(b - nC - nA, nfeat_mid, W_mid, b_mid, attn_edge, nullptr, 1, N,
                      mr16, em, nullptr, Xbf, WT, av0sh, av1sh, bsh);
    } else {
        int i = (b - nC - nA - nB) * 256 + threadIdx.x;
        if (i < E) atomicAdd(&deg[dst_idx[i]], 1);
    }
}

// ---------------------------------------------------------------------------
__global__ __launch_bounds__(256) void scanA_kernel(
    const int* __restrict__ deg, int* __restrict__ blkSums, int N)
{
    __shared__ int red[256];
    int t = threadIdx.x;
    int base = blockIdx.x * 1024 + t * 4;
    int s = 0;
    if (base + 3 < N) {
        int4 v = *(const int4*)&deg[base];
        s = v.x + v.y + v.z + v.w;
    } else {
        for (int i = 0; i < 4; ++i) if (base + i < N) s += deg[base + i];
    }
    red[t] = s;
    __syncthreads();
    for (int off = 128; off >= 1; off >>= 1) {
        if (t < off) red[t] += red[t + off];
        __syncthreads();
    }
    if (t == 0) blkSums[blockIdx.x] = red[0];
}

// ---------------------------------------------------------------------------
__global__ __launch_bounds__(256) void scanC_kernel(
    const int* __restrict__ deg, const int* __restrict__ blkSums,
    int* __restrict__ row_ptr, int* __restrict__ cursor, int N, int nblk)
{
    __shared__ int sh[256];
    __shared__ int blkOffSh;
    int t = threadIdx.x;
    int blk = blockIdx.x;
    int base = blk * 1024 + t * 4;

    if (t < 64) {
        int s = 0;
        for (int j = t; j < blk; j += 64) s += blkSums[j];
        for (int m = 32; m >= 1; m >>= 1) s += __shfl_xor(s, m, 64);
        if (t == 0) blkOffSh = s;
    }

    int4 v = make_int4(0, 0, 0, 0);
    if (base + 3 < N) v = *(const int4*)&deg[base];
    else {
        if (base < N)     v.x = deg[base];
        if (base + 1 < N) v.y = deg[base + 1];
        if (base + 2 < N) v.z = deg[base + 2];
    }
    int ts = v.x + v.y + v.z + v.w;
    sh[t] = ts;
    __syncthreads();
    for (int off = 1; off < 256; off <<= 1) {
        int val = (t >= off) ? sh[t - off] : 0;
        __syncthreads();
        sh[t] += val;
        __syncthreads();
    }
    int blkOff = blkOffSh;
    int ex = blkOff + ((t == 0) ? 0 : sh[t - 1]);
    int p0 = ex, p1 = ex + v.x, p2 = p1 + v.y, p3 = p2 + v.z;
    if (base < N)     { row_ptr[base]     = p0; cursor[base]     = p0; }
    if (base + 1 < N) { row_ptr[base + 1] = p1; cursor[base + 1] = p1; }
    if (base + 2 < N) { row_ptr[base + 2] = p2; cursor[base + 2] = p2; }
    if (base + 3 < N) { row_ptr[base + 3] = p3; cursor[base + 3] = p3; }
    if (blk == nblk - 1 && t == 255) row_ptr[N] = blkOff + sh[255];
}

// ---------------------------------------------------------------------------
// Fused edge-logit + CSR scatter. One packed 16B record per edge:
//   { src | (hn<<16), he, e_head0_bits, e_head1_bits }  (log2 domain, ±60 clamp)
// ---------------------------------------------------------------------------
__global__ __launch_bounds__(256) void scatter_kernel(
    const int* __restrict__ src, const int* __restrict__ dst,
    const int* __restrict__ hn, const int* __restrict__ he,
    const float2* __restrict__ es, const float2* __restrict__ ed,
    const float2* __restrict__ em, const float2* __restrict__ er,
    int* __restrict__ cursor, uint4* __restrict__ erec, int E)
{
    int i = blockIdx.x * blockDim.x + threadIdx.x;
    if (i >= E) return;
    int s = src[i], d = dst[i], a = hn[i], b = he[i];
    float2 v1 = es[s], v2 = ed[d], v3 = em[a], v4 = er[b];
    float e0 = fminf(fmaxf(v1.x + v2.x + v3.x + v4.x, -60.f), 60.f);
    float e1 = fminf(fmaxf(v1.y + v2.y + v3.y + v4.y, -60.f), 60.f);
    int pos = atomicAdd(&cursor[d], 1);
    erec[pos] = make_uint4((uint)s | ((uint)a << 16), (uint)b,
                           __float_as_uint(e0), __float_as_uint(e1));
}

// ---------------------------------------------------------------------------
// Per-node aggregation: FOUR independent quarter-chains (R8 lesson: the
// scheduler respects structural independence; 12 outstanding gathers).
// mr16 = combined mid+rel table (uniform base -> saddr addressing).
// ---------------------------------------------------------------------------
__global__ __launch_bounds__(256) void aggregate_kernel(
    const int* __restrict__ row_ptr, const uint4* __restrict__ erec,
    const unsigned short* __restrict__ hp16,
    const unsigned short* __restrict__ mr16,
    const float* __restrict__ We, const float* __restrict__ be,
    float* __restrict__ out, int N)
{
    __shared__ float WeSh[64 * 32];
    __shared__ float ft2sh[4][128];
    int t = threadIdx.x;
    for (int i = t; i < 64 * 32; i += 256) WeSh[i] = We[i];
    __syncthreads();

    int wave = t >> 6, lane = t & 63;
    int head = lane >> 5, dj = lane & 31;
    int n = blockIdx.x * 4 + wave;
    bool valid = n < N;
    int nn = valid ? n : 0;

    int start = row_ptr[nn], end = row_ptr[nn + 1];
    int cnt = end - start;
    int len = cnt >> 2;
    int s0 = start, s1 = s0 + len, s2 = s1 + len, s3 = s2 + len;

    bool isrel = lane >= 32;
    uint l31 = (uint)(lane & 31);
    bool h1w = ((lane >> 4) & 1) != 0;
    uint Nu = (uint)N;
    const uint* mr32 = (const uint*)mr16;

    float d0A = 0.f, d1A = 0.f, rsA = 0.f, fxA = 0.f, fyA = 0.f;
    float d0B = 0.f, d1B = 0.f, rsB = 0.f, fxB = 0.f, fyB = 0.f;
    float d0C = 0.f, d1C = 0.f, rsC = 0.f, fxC = 0.f, fyC = 0.f;
    float d0D = 0.f, d1D = 0.f, rsD = 0.f, fxD = 0.f, fyD = 0.f;

    auto edge = [&](const uint4& r, uint hu, uint pv, float& d0, float& d1,
                    float& rs, float& fx, float& fy) {
        float a0 = __builtin_amdgcn_exp2f(__uint_as_float(r.z));
        float a1 = __builtin_amdgcn_exp2f(__uint_as_float(r.w));
        d0 += a0; d1 += a1;
        rs += bf16u(hu) * (head ? a1 : a0);
        float w = h1w ? a1 : a0;
        fx += bf16_lo(pv) * w;
        fy += bf16_hi(pv) * w;
    };

    for (int k = 0; k < len; ++k) {
        uint4 rA = erec[s0 + k];
        uint4 rB = erec[s1 + k];
        uint4 rC = erec[s2 + k];
        uint4 rD = erec[s3 + k];
        uint huA = (uint)hp16[((rA.x & 0xffffu) << 6) | (uint)lane];
        uint huB = (uint)hp16[((rB.x & 0xffffu) << 6) | (uint)lane];
        uint huC = (uint)hp16[((rC.x & 0xffffu) << 6) | (uint)lane];
        uint huD = (uint)hp16[((rD.x & 0xffffu) << 6) | (uint)lane];
        uint rowA = isrel ? (rA.y + Nu) : (rA.x >> 16);
        uint rowB = isrel ? (rB.y + Nu) : (rB.x >> 16);
        uint rowC = isrel ? (rC.y + Nu) : (rC.x >> 16);
        uint rowD = isrel ? (rD.y + Nu) : (rD.x >> 16);
        uint pvA = mr32[(rowA << 5) | l31];
        uint pvB = mr32[(rowB << 5) | l31];
        uint pvC = mr32[(rowC << 5) | l31];
        uint pvD = mr32[(rowD << 5) | l31];
        edge(rA, huA, pvA, d0A, d1A, rsA, fxA, fyA);
        edge(rB, huB, pvB, d0B, d1B, rsB, fxB, fyB);
        edge(rC, huC, pvC, d0C, d1C, rsC, fxC, fyC);
        edge(rD, huD, pvD, d0D, d1D, rsD, fxD, fyD);
    }
    for (int i = s3 + len; i < end; ++i) {     // tail: 0..3 edges
        uint4 r = erec[i];
        uint hu = (uint)hp16[((r.x & 0xffffu) << 6) | (uint)lane];
        uint row = isrel ? (r.y + Nu) : (r.x >> 16);
        uint pv = mr32[(row << 5) | l31];
        edge(r, hu, pv, d0A, d1A, rsA, fxA, fyA);
    }

    float den0 = (d0A + d0B) + (d0C + d0D);
    float den1 = (d1A + d1B) + (d1C + d1D);
    float rstc = (rsA + rsB) + (rsC + rsD);
    float fx   = (fxA + fxB) + (fxC + fxD);
    float fy   = (fyA + fyB) + (fyC + fyD);

    float inv0 = den0 > 0.f ? 1.f / den0 : 0.f;
    float inv1 = den1 > 0.f ? 1.f / den1 : 0.f;
    rstc *= head ? inv1 : inv0;
    float invf = h1w ? inv1 : inv0;

    int slotbase;
    if (lane < 16)      slotbase = 2 * lane;
    else if (lane < 32) slotbase = 2 * lane + 32;
    else if (lane < 48) slotbase = 2 * lane - 32;
    else                slotbase = 2 * lane;
    ft2sh[wave][slotbase]     = fx * invf;
    ft2sh[wave][slotbase + 1] = fy * invf;

    // wave-local LDS fence (ft2sh region is per-wave)
    __builtin_amdgcn_sched_barrier(0);
    asm volatile("s_waitcnt lgkmcnt(0)" ::: "memory");
    __builtin_amdgcn_sched_barrier(0);

    float fc = be[dj];
#pragma unroll 8
    for (int dd = 0; dd < 64; ++dd)
        fc += ft2sh[wave][head * 64 + dd] * WeSh[dd * 32 + dj];

    float val = rstc + fc + bf16u((uint)hp16[(uint)nn * 64 + (uint)lane]);
    val = fmaxf(val, 0.f);

    float ss = val * val;
    for (int m = 32; m >= 1; m >>= 1) ss += __shfl_xor(ss, m, 64);
    float invn = 1.f / fmaxf(sqrtf(ss), 1e-12f);
    if (valid) out[(uint)nn * 64 + lane] = val * invn;
}

// ---------------------------------------------------------------------------
extern "C" void kernel_launch(void* const* d_in, const int* in_sizes, int n_in,
                              void* d_out, int out_size, void* d_ws, size_t ws_size,
                              hipStream_t stream)
{
    const float* h         = (const float*)d_in[0];
    const float* W_t       = (const float*)d_in[1];
    const float* b_t       = (const float*)d_in[2];
    const float* nfeat_mid = (const float*)d_in[3];
    const float* W_mid     = (const float*)d_in[4];
    const float* b_mid     = (const float*)d_in[5];
    const float* efeat_rel = (const float*)d_in[6];
    const float* W_rel     = (const float*)d_in[7];
    const float* b_rel     = (const float*)d_in[8];
    const float* attn_src  = (const float*)d_in[9];
    const float* attn_dst  = (const float*)d_in[10];
    const float* attn_edge = (const float*)d_in[11];
    const float* W_edge    = (const float*)d_in[12];
    const float* b_edge    = (const float*)d_in[13];
    const int* src_idx     = (const int*)d_in[14];
    const int* dst_idx     = (const int*)d_in[15];
    const int* hn          = (const int*)d_in[16];
    const int* he          = (const int*)d_in[17];
    float* out = (float*)d_out;

    const int N    = in_sizes[0] / 64;
    const int EREL = in_sizes[6] / 32;
    const int E    = in_sizes[14];

    char* ws = (char*)d_ws;
    auto alloc = [&](size_t bytes) {
        void* p = (void*)ws;
        ws += (bytes + 255) & ~(size_t)255;
        return p;
    };
    unsigned short* hp16  = (unsigned short*)alloc((size_t)N * 64 * 2);
    unsigned short* mr16  = (unsigned short*)alloc((size_t)(N + EREL) * 64 * 2); // mid rows [0,N), rel rows [N, N+EREL)
    float2* e_src  = (float2*)alloc((size_t)N * 8);
    float2* e_dst  = (float2*)alloc((size_t)N * 8);
    float2* em     = (float2*)alloc((size_t)N * 8);
    float2* er     = (float2*)alloc((size_t)EREL * 8);
    int* deg       = (int*)alloc((size_t)N * 4);
    int* row_ptr   = (int*)alloc((size_t)(N + 1) * 4);
    int* cursor    = (int*)alloc((size_t)N * 4);
    int* blkSums   = (int*)alloc((size_t)64 * 4);
    uint4* erec    = (uint4*)alloc((size_t)E * 16);

    hipMemsetAsync(deg, 0, (size_t)N * 4, stream);

    int nA = (N + 63) / 64;
    int nB = nA;
    int nC = (EREL + 63) / 64;
    int nD = (E + 255) / 256;
    mega_kernel<<<nC + nA + nB + nD, 256, 0, stream>>>(
        h, W_t, b_t, nfeat_mid, W_mid, b_mid, efeat_rel, W_rel, b_rel,
        attn_src, attn_dst, attn_edge, dst_idx, deg,
        hp16, mr16, e_src, e_dst, em, er,
        N, EREL, E, nC, nA, nB);

    int nblk = (N + 1023) / 1024;
    scanA_kernel<<<nblk, 256, 0, stream>>>(deg, blkSums, N);
    scanC_kernel<<<nblk, 256, 0, stream>>>(deg, blkSums, row_ptr, cursor, N, nblk);

    scatter_kernel<<<(E + 255) / 256, 256, 0, stream>>>(
        src_idx, dst_idx, hn, he, e_src, e_dst, em, er, cursor, erec, E);

    aggregate_kernel<<<(N + 3) / 4, 256, 0, stream>>>(
        row_ptr, erec, hp16, mr16, W_edge, b_edge, out, N);
}